// Round 10
// baseline (371.543 us; speedup 1.0000x reference)
//
#include <hip/hip_runtime.h>
#include <math.h>

#define N_NODES 100000
#define N_EDGES 1600000
#define NFEAT 64
#define NCLASS 40

#define SCAN_CHUNK 1024
#define SCAN_BLOCKS ((N_NODES + SCAN_CHUNK - 1) / SCAN_CHUNK)  // 98

#define NRANGES 8
#define RSZ ((N_NODES + NRANGES - 1) / NRANGES)  // 12500
#define FILL_SLOTS 64

__device__ __forceinline__ float bf2f(unsigned short u) {
  return __uint_as_float(((unsigned int)u) << 16);
}
__device__ __forceinline__ unsigned short f2bf(float f) {
  unsigned int u = __float_as_uint(f);
  u += 0x7FFFu + ((u >> 16) & 1u);  // RNE
  return (unsigned short)(u >> 16);
}

// ---------------------------------------------------------------------------
// Pass A: histogram over dst + per-edge rank (ushort) + x->bf16 convert fused.
// Thread e: one edge (atomic) + one float4 quad of x (N_EDGES == N*F/4).
// ---------------------------------------------------------------------------
__global__ __launch_bounds__(256) void hist_rank_cvt_k(
    const int* __restrict__ dst, int* __restrict__ deg,
    unsigned short* __restrict__ rank, const float* __restrict__ x,
    unsigned short* __restrict__ xb) {
  int e = blockIdx.x * 256 + threadIdx.x;
  if (e < N_EDGES) {
    rank[e] = (unsigned short)atomicAdd(&deg[dst[e]], 1);
    float4 v = reinterpret_cast<const float4*>(x)[e];
    ushort4 o;
    o.x = f2bf(v.x); o.y = f2bf(v.y); o.z = f2bf(v.z); o.w = f2bf(v.w);
    reinterpret_cast<ushort4*>(xb)[e] = o;
  }
}

// Pass 1: per-block chunk sums
__global__ __launch_bounds__(256) void scan_partial_k(
    const int* __restrict__ deg, int* __restrict__ blockSums) {
  __shared__ int red[256];
  int b = blockIdx.x, t = threadIdx.x;
  int base = b * SCAN_CHUNK;
  int s = 0;
  for (int i = t; i < SCAN_CHUNK; i += 256) {
    int idx = base + i;
    if (idx < N_NODES) s += deg[idx];
  }
  red[t] = s;
  __syncthreads();
  for (int off = 128; off; off >>= 1) {
    if (t < off) red[t] += red[t + off];
    __syncthreads();
  }
  if (t == 0) blockSums[b] = red[0];
}

// Pass 2: one small block scans the 98 partials
__global__ __launch_bounds__(128) void scan_sums_k(int* __restrict__ blockSums,
                                                   int* __restrict__ offs) {
  __shared__ int part[128];
  int t = threadIdx.x;
  int v = (t < SCAN_BLOCKS) ? blockSums[t] : 0;
  part[t] = v;
  __syncthreads();
  for (int off = 1; off < 128; off <<= 1) {
    int add = (t >= off) ? part[t - off] : 0;
    __syncthreads();
    part[t] += add;
    __syncthreads();
  }
  if (t < SCAN_BLOCKS) blockSums[t] = (t == 0) ? 0 : part[t - 1];
  if (t == 127) offs[N_NODES] = part[127];  // == N_EDGES
}

// Pass 3: intra-chunk exclusive scan + block prefix -> offs
__global__ __launch_bounds__(256) void scan_final_k(
    const int* __restrict__ deg, const int* __restrict__ blockOffs,
    int* __restrict__ offs) {
  __shared__ int part[256];
  int b = blockIdx.x, t = threadIdx.x;
  int base = b * SCAN_CHUNK + t * 4;
  int v0 = 0, v1 = 0, v2 = 0, v3 = 0;
  if (base + 3 < N_NODES) {
    v0 = deg[base]; v1 = deg[base + 1]; v2 = deg[base + 2]; v3 = deg[base + 3];
  } else {
    if (base + 0 < N_NODES) v0 = deg[base + 0];
    if (base + 1 < N_NODES) v1 = deg[base + 1];
    if (base + 2 < N_NODES) v2 = deg[base + 2];
    if (base + 3 < N_NODES) v3 = deg[base + 3];
  }
  part[t] = v0 + v1 + v2 + v3;
  __syncthreads();
  for (int off = 1; off < 256; off <<= 1) {
    int add = (t >= off) ? part[t - off] : 0;
    __syncthreads();
    part[t] += add;
    __syncthreads();
  }
  int run = blockOffs[b] + ((t == 0) ? 0 : part[t - 1]);
  if (base + 0 < N_NODES) { offs[base + 0] = run; run += v0; }
  if (base + 1 < N_NODES) { offs[base + 1] = run; run += v1; }
  if (base + 2 < N_NODES) { offs[base + 2] = run; run += v2; }
  if (base + 3 < N_NODES) { offs[base + 3] = run; run += v3; }
}

// ---------------------------------------------------------------------------
// Pass B: XCD-partitioned atomic-free CSR fill.
// 8 node-ranges x FILL_SLOTS blocks. Blocks with (blockIdx&7)==r write only
// edges with dst in range r -> each XCD's csr slice (~800KB) stays L2-resident
// and scattered-line evictions collapse (~105MB -> ~8MB writebacks).
// Each range-group reads the full edge list once (sequential, L3-resident).
// Correct regardless of actual block->XCD placement.
// ---------------------------------------------------------------------------
__global__ __launch_bounds__(256) void fill_csr_xcd_k(
    const int* __restrict__ src, const int* __restrict__ dst,
    const unsigned short* __restrict__ rank, const int* __restrict__ offs,
    int* __restrict__ csr) {
  const int NQ = N_EDGES / 4;  // 400000
  int range = blockIdx.x & (NRANGES - 1);
  int slot = blockIdx.x >> 3;  // 0..FILL_SLOTS-1
  unsigned int lo = range * RSZ;

  for (int q = slot * 256 + threadIdx.x; q < NQ; q += FILL_SLOTS * 256) {
    int e = q << 2;
    int4 s = *reinterpret_cast<const int4*>(src + e);
    int4 d = *reinterpret_cast<const int4*>(dst + e);
    ushort4 r = *reinterpret_cast<const ushort4*>(rank + e);
    if ((unsigned int)(d.x - lo) < (unsigned int)RSZ) csr[offs[d.x] + r.x] = s.x;
    if ((unsigned int)(d.y - lo) < (unsigned int)RSZ) csr[offs[d.y] + r.y] = s.y;
    if ((unsigned int)(d.z - lo) < (unsigned int)RSZ) csr[offs[d.z] + r.z] = s.z;
    if ((unsigned int)(d.w - lo) < (unsigned int)RSZ) csr[offs[d.w] + r.w] = s.w;
  }
}

// ---------------------------------------------------------------------------
// Gather (bf16 in, fp32 accum, bf16 out): agg[r] = h[r] + sum_{s in N(r)} h[s]
// One wave per node; 4 edge-groups x 16 lanes; lane covers 4 feats; unroll x2.
// ---------------------------------------------------------------------------
__global__ __launch_bounds__(256) void gather_b_k(
    const unsigned short* __restrict__ hb, const int* __restrict__ offs,
    const int* __restrict__ csr, unsigned short* __restrict__ aggb) {
  int t = threadIdx.x;
  int wv = t >> 6;
  int lane = t & 63;
  int g = lane >> 4;   // edge-group 0..3
  int l = lane & 15;   // feature quad 0..15
  int node = blockIdx.x * 4 + wv;
  if (node >= N_NODES) return;

  int beg = offs[node], end = offs[node + 1];
  float a0 = 0.f, a1 = 0.f, a2 = 0.f, a3 = 0.f;
  int e = beg + g;
  for (; e + 4 < end; e += 8) {
    int s0 = csr[e];
    int s1 = csr[e + 4];
    ushort4 u0 = *reinterpret_cast<const ushort4*>(hb + (size_t)s0 * NFEAT + (l << 2));
    ushort4 u1 = *reinterpret_cast<const ushort4*>(hb + (size_t)s1 * NFEAT + (l << 2));
    a0 += bf2f(u0.x) + bf2f(u1.x);
    a1 += bf2f(u0.y) + bf2f(u1.y);
    a2 += bf2f(u0.z) + bf2f(u1.z);
    a3 += bf2f(u0.w) + bf2f(u1.w);
  }
  if (e < end) {
    int s = csr[e];
    ushort4 u = *reinterpret_cast<const ushort4*>(hb + (size_t)s * NFEAT + (l << 2));
    a0 += bf2f(u.x); a1 += bf2f(u.y); a2 += bf2f(u.z); a3 += bf2f(u.w);
  }
  a0 += __shfl_xor(a0, 16); a1 += __shfl_xor(a1, 16);
  a2 += __shfl_xor(a2, 16); a3 += __shfl_xor(a3, 16);
  a0 += __shfl_xor(a0, 32); a1 += __shfl_xor(a1, 32);
  a2 += __shfl_xor(a2, 32); a3 += __shfl_xor(a3, 32);

  if (g == 0) {
    ushort4 u = *reinterpret_cast<const ushort4*>(hb + (size_t)node * NFEAT + (l << 2));
    ushort4 o;
    o.x = f2bf(a0 + bf2f(u.x)); o.y = f2bf(a1 + bf2f(u.y));
    o.z = f2bf(a2 + bf2f(u.z)); o.w = f2bf(a3 + bf2f(u.w));
    *reinterpret_cast<ushort4*>(aggb + (size_t)node * NFEAT + (l << 2)) = o;
  }
}

// ---------------------------------------------------------------------------
// Layer-1 linear (bf16 in, bf16 out): out = relu(in @ W + b)
// Transposed W in LDS; float4 k-vectorized reads.
// ---------------------------------------------------------------------------
__global__ __launch_bounds__(256) void linear_relu_b_k(
    const unsigned short* __restrict__ inb, const float* __restrict__ W,
    const float* __restrict__ b, unsigned short* __restrict__ outb) {
  __shared__ float sIn[32][68];
  __shared__ float sWT[64][68];  // sWT[c][k]
  int r0 = blockIdx.x * 32;
  int t = threadIdx.x;
  for (int i = t; i < 64 * 64; i += 256) {
    int k = i >> 6, c = i & 63;
    sWT[c][k] = W[i];
  }
  for (int i = t; i < 512; i += 256) {
    int r = i >> 4, q = i & 15;
    ushort4 u = *reinterpret_cast<const ushort4*>(
        inb + (size_t)(r0 + r) * NFEAT + (q << 2));
    float4 v;
    v.x = bf2f(u.x); v.y = bf2f(u.y); v.z = bf2f(u.z); v.w = bf2f(u.w);
    *reinterpret_cast<float4*>(&sIn[r][q << 2]) = v;
  }
  __syncthreads();

  int c = t & 63;
  int rb = t >> 6;
  float acc[8];
#pragma unroll
  for (int i = 0; i < 8; ++i) acc[i] = 0.f;
#pragma unroll
  for (int kq = 0; kq < 16; ++kq) {
    float4 w = *reinterpret_cast<const float4*>(&sWT[c][kq << 2]);
#pragma unroll
    for (int i = 0; i < 8; ++i) {
      float4 v = *reinterpret_cast<const float4*>(&sIn[rb * 8 + i][kq << 2]);
      acc[i] = fmaf(v.x, w.x, fmaf(v.y, w.y, fmaf(v.z, w.z, fmaf(v.w, w.w, acc[i]))));
    }
  }
  float bias = b[c];
#pragma unroll
  for (int i = 0; i < 8; ++i) {
    int gr = r0 + rb * 8 + i;
    outb[(size_t)gr * NFEAT + c] = f2bf(fmaxf(acc[i] + bias, 0.f));
  }
}

// ---------------------------------------------------------------------------
// Fused layer-2 linear + final linear + log_softmax (bf16 agg in).
// ---------------------------------------------------------------------------
__global__ __launch_bounds__(256) void fused_l2_final_k(
    const unsigned short* __restrict__ inb, const float* __restrict__ W2,
    const float* __restrict__ b2, const float* __restrict__ Wf,
    const float* __restrict__ bf, float* __restrict__ out) {
  __shared__ float sIn[32][68];
  __shared__ float sWT[64][68];      // W2^T
  __shared__ float sWfT[NCLASS][68]; // Wf^T
  __shared__ float sH[32][68];
  __shared__ float sLse[32];
  float (*sLg)[41] = reinterpret_cast<float(*)[41]>(&sIn[0][0]);  // alias

  int r0 = blockIdx.x * 32;
  int t = threadIdx.x;
  int c = t & 63;
  int rb = t >> 6;

  for (int i = t; i < 64 * 64; i += 256) {
    int k = i >> 6, cc = i & 63;
    sWT[cc][k] = W2[i];
  }
  for (int i = t; i < 64 * NCLASS; i += 256) {
    int k = i / NCLASS, cc = i - k * NCLASS;
    sWfT[cc][k] = Wf[i];
  }
  for (int i = t; i < 512; i += 256) {
    int r = i >> 4, q = i & 15;
    ushort4 u = *reinterpret_cast<const ushort4*>(
        inb + (size_t)(r0 + r) * NFEAT + (q << 2));
    float4 v;
    v.x = bf2f(u.x); v.y = bf2f(u.y); v.z = bf2f(u.z); v.w = bf2f(u.w);
    *reinterpret_cast<float4*>(&sIn[r][q << 2]) = v;
  }
  __syncthreads();

  // P1: h2 = relu(agg @ W2 + b2) -> sH
  float acc[8];
#pragma unroll
  for (int i = 0; i < 8; ++i) acc[i] = 0.f;
#pragma unroll
  for (int kq = 0; kq < 16; ++kq) {
    float4 w = *reinterpret_cast<const float4*>(&sWT[c][kq << 2]);
#pragma unroll
    for (int i = 0; i < 8; ++i) {
      float4 v = *reinterpret_cast<const float4*>(&sIn[rb * 8 + i][kq << 2]);
      acc[i] = fmaf(v.x, w.x, fmaf(v.y, w.y, fmaf(v.z, w.z, fmaf(v.w, w.w, acc[i]))));
    }
  }
  float bias = b2[c];
#pragma unroll
  for (int i = 0; i < 8; ++i)
    sH[rb * 8 + i][c] = fmaxf(acc[i] + bias, 0.f);
  __syncthreads();

  // P2: logits = h2 @ Wf + bf -> sLg (aliases sIn; sIn dead after barrier)
  if (c < NCLASS) {
    float lg[8];
    float bfc = bf[c];
#pragma unroll
    for (int i = 0; i < 8; ++i) lg[i] = bfc;
#pragma unroll
    for (int kq = 0; kq < 16; ++kq) {
      float4 w = *reinterpret_cast<const float4*>(&sWfT[c][kq << 2]);
#pragma unroll
      for (int i = 0; i < 8; ++i) {
        float4 v = *reinterpret_cast<const float4*>(&sH[rb * 8 + i][kq << 2]);
        lg[i] = fmaf(v.x, w.x, fmaf(v.y, w.y, fmaf(v.z, w.z, fmaf(v.w, w.w, lg[i]))));
      }
    }
#pragma unroll
    for (int i = 0; i < 8; ++i) sLg[rb * 8 + i][c] = lg[i];
  }
  __syncthreads();

  // P3: per-row logsumexp
  if (t < 32) {
    float m = -INFINITY;
#pragma unroll
    for (int j = 0; j < NCLASS; ++j) m = fmaxf(m, sLg[t][j]);
    float s = 0.f;
#pragma unroll
    for (int j = 0; j < NCLASS; ++j) s += expf(sLg[t][j] - m);
    sLse[t] = m + logf(s);
  }
  __syncthreads();

  // Coalesced output: 32 rows = 1280 contiguous floats
  for (int i = t; i < 32 * NCLASS; i += 256) {
    int r = i / NCLASS, cc = i - r * NCLASS;
    out[(size_t)(r0 + r) * NCLASS + cc] = sLg[r][cc] - sLse[r];
  }
}

// ---------------------------------------------------------------------------
extern "C" void kernel_launch(void* const* d_in, const int* in_sizes, int n_in,
                              void* d_out, int out_size, void* d_ws, size_t ws_size,
                              hipStream_t stream) {
  const float* x  = (const float*)d_in[0];
  const int*   ei = (const int*)d_in[1];  // [2, N_EDGES] as int32
  const float* W1 = (const float*)d_in[2];
  const float* b1 = (const float*)d_in[3];
  const float* W2 = (const float*)d_in[4];
  const float* b2 = (const float*)d_in[5];
  const float* Wf = (const float*)d_in[6];
  const float* bf = (const float*)d_in[7];
  float* out = (float*)d_out;

  const int* src = ei;
  const int* dst = ei + N_EDGES;

  const size_t featElems = (size_t)N_NODES * NFEAT;  // 6.4M
  unsigned short* xb   = (unsigned short*)d_ws;      // bf16 x
  unsigned short* h1b  = xb + featElems;             // bf16 h1
  unsigned short* aggA = h1b + featElems;            // bf16 agg1
  unsigned short* aggC = aggA + featElems;           // bf16 agg2
  unsigned short* rank = aggC + featElems;           // ushort, N_EDGES
  int* deg       = (int*)(rank + N_EDGES);
  int* offs      = deg + N_NODES;                    // N_NODES+1
  int* blockSums = offs + N_NODES + 1;               // 128
  int* csr       = blockSums + 128;                  // N_EDGES

  const int edgeBlocks   = (N_EDGES + 255) / 256;    // 6250
  const int gatherBlocks = (N_NODES + 3) / 4;        // 25000
  const int linBlocks    = (N_NODES + 31) / 32;      // 3125

  // Build dst-CSR (+ fused x->bf16 convert)
  hipMemsetAsync(deg, 0, N_NODES * sizeof(int), stream);
  hist_rank_cvt_k<<<edgeBlocks, 256, 0, stream>>>(dst, deg, rank, x, xb);
  scan_partial_k<<<SCAN_BLOCKS, 256, 0, stream>>>(deg, blockSums);
  scan_sums_k<<<1, 128, 0, stream>>>(blockSums, offs);
  scan_final_k<<<SCAN_BLOCKS, 256, 0, stream>>>(deg, blockSums, offs);
  fill_csr_xcd_k<<<NRANGES * FILL_SLOTS, 256, 0, stream>>>(src, dst, rank, offs, csr);

  // Layer 1: xb --gather--> aggA --linear--> h1b
  gather_b_k<<<gatherBlocks, 256, 0, stream>>>(xb, offs, csr, aggA);
  linear_relu_b_k<<<linBlocks, 256, 0, stream>>>(aggA, W1, b1, h1b);

  // Layer 2 + final + logsoftmax
  gather_b_k<<<gatherBlocks, 256, 0, stream>>>(h1b, offs, csr, aggC);
  fused_l2_final_k<<<linBlocks, 256, 0, stream>>>(aggC, W2, b2, Wf, bf, out);
}